// Round 3
// baseline (2666.688 us; speedup 1.0000x reference)
//
#include <hip/hip_runtime.h>

// Fused shifted-window cross-attention (Swin-style), fp32, occupancy-tuned.
// One block per 8x8 window (2048 blocks, 256 threads), 2 blocks/CU.
// LDS (76 KiB): x-window [64][196] + Q/K/V tiles [64][36] (O reuses Q tile).
// Weights + b-window + rel-bias read directly from global (uniform or L2-hot).
// [resubmit of round-1 source: both prior rounds died on GPU acquisition,
//  kernel itself has never executed]

#define NHEADS 6
#define CDIM 192
#define IMG 256
#define SHIFTV 4
#define SCALE_F 0.17677669529663687f

#define XPITCH 196   // 196 % 32 == 4 -> row-major b128 column reads conflict-free
#define HPITCH 36    // 36 % 32 == 4

// GEMM, source rows in LDS (x window), weights global (wave-uniform loads).
__device__ __forceinline__ void gemmL(const float* __restrict__ src,   // LDS [64][XPITCH]
                                      const float* __restrict__ w,     // global [32][192] slice
                                      const float* __restrict__ bias,  // global, 32
                                      float* __restrict__ dst,         // LDS [64][HPITCH]
                                      int t)
{
    const int r = t & 63;
    const int cb = (t >> 6) << 3;            // 0,8,16,24 (wave-uniform)
    float acc[8];
#pragma unroll
    for (int j = 0; j < 8; ++j) acc[j] = bias[cb + j];
    const float4* xr = (const float4*)(src + r * XPITCH);
    const float4* wp[8];
#pragma unroll
    for (int j = 0; j < 8; ++j) wp[j] = (const float4*)(w + (cb + j) * CDIM);
#pragma unroll 2
    for (int k4 = 0; k4 < 48; ++k4) {
        const float4 xv = xr[k4];
#pragma unroll
        for (int j = 0; j < 8; ++j) {
            const float4 wv = wp[j][k4];     // imm-offset loads, no addr arith
            acc[j] = fmaf(xv.x, wv.x, acc[j]);
            acc[j] = fmaf(xv.y, wv.y, acc[j]);
            acc[j] = fmaf(xv.z, wv.z, acc[j]);
            acc[j] = fmaf(xv.w, wv.w, acc[j]);
        }
    }
    float4* d4 = (float4*)(dst + r * HPITCH + cb);
    d4[0] = make_float4(acc[0], acc[1], acc[2], acc[3]);
    d4[1] = make_float4(acc[4], acc[5], acc[6], acc[7]);
}

// GEMM, source rows in global (b window), weights global.
__device__ __forceinline__ void gemmG(const float4* __restrict__ xr,   // global row base (lane's row)
                                      const float* __restrict__ w,
                                      const float* __restrict__ bias,
                                      float* __restrict__ dst,
                                      int t)
{
    const int r = t & 63;
    const int cb = (t >> 6) << 3;
    float acc[8];
#pragma unroll
    for (int j = 0; j < 8; ++j) acc[j] = bias[cb + j];
    const float4* wp[8];
#pragma unroll
    for (int j = 0; j < 8; ++j) wp[j] = (const float4*)(w + (cb + j) * CDIM);
#pragma unroll 4
    for (int k4 = 0; k4 < 48; ++k4) {
        const float4 xv = xr[k4];
#pragma unroll
        for (int j = 0; j < 8; ++j) {
            const float4 wv = wp[j][k4];
            acc[j] = fmaf(xv.x, wv.x, acc[j]);
            acc[j] = fmaf(xv.y, wv.y, acc[j]);
            acc[j] = fmaf(xv.z, wv.z, acc[j]);
            acc[j] = fmaf(xv.w, wv.w, acc[j]);
        }
    }
    float4* d4 = (float4*)(dst + r * HPITCH + cb);
    d4[0] = make_float4(acc[0], acc[1], acc[2], acc[3]);
    d4[1] = make_float4(acc[4], acc[5], acc[6], acc[7]);
}

// Attention for one head. Reads Q from sQO, K,V from LDS; writes O back into sQO.
// Contains ONE internal __syncthreads (all 256 threads reach it).
__device__ __forceinline__ void attnHead(float* __restrict__ sQO,
                                         const float* __restrict__ sK,
                                         const float* __restrict__ sV,
                                         const float* __restrict__ relh,  // global
                                         bool lastrow, bool lastcol, int t)
{
    const int p = t >> 2;                    // query row, 4 lanes per row (same wave)
    const int qg = t & 3;                    // key-column group
    const int pr = p >> 3, pc = p & 7;
    const float4* q4 = (const float4*)(sQO + p * HPITCH);
    float4 qreg[8];
#pragma unroll
    for (int d = 0; d < 8; ++d) qreg[d] = q4[d];

    __syncthreads();                         // all Q reads done -> sQO reusable for O

    float s[16];
#pragma unroll
    for (int j = 0; j < 16; ++j) {
        const int q = (j << 2) + qg;         // keys q ≡ qg (mod 4)
        const float4* k4 = (const float4*)(sK + q * HPITCH);
        float a = 0.f;
#pragma unroll
        for (int d = 0; d < 8; ++d) {
            const float4 kv = k4[d];
            a = fmaf(qreg[d].x, kv.x, a);
            a = fmaf(qreg[d].y, kv.y, a);
            a = fmaf(qreg[d].z, kv.z, a);
            a = fmaf(qreg[d].w, kv.w, a);
        }
        const int qr = q >> 3, qc = q & 7;
        const float bias = relh[(pr - qr + 7) * 15 + (pc - qc + 7)];
        const bool msk = (lastrow && ((pr < 4) != (qr < 4))) ||
                         (lastcol && ((pc < 4) != (qc < 4)));
        s[j] = msk ? -1e30f : fmaf(a, SCALE_F, bias);
    }

    // softmax over 64 keys spread across 4 consecutive lanes (same wave)
    float m = s[0];
#pragma unroll
    for (int j = 1; j < 16; ++j) m = fmaxf(m, s[j]);
    m = fmaxf(m, __shfl_xor(m, 1));
    m = fmaxf(m, __shfl_xor(m, 2));
    float sum = 0.f;
#pragma unroll
    for (int j = 0; j < 16; ++j) { s[j] = __expf(s[j] - m); sum += s[j]; }
    sum += __shfl_xor(sum, 1);
    sum += __shfl_xor(sum, 2);
    const float inv = 1.0f / sum;

    float4 part[8];
#pragma unroll
    for (int d = 0; d < 8; ++d) part[d] = make_float4(0.f, 0.f, 0.f, 0.f);
#pragma unroll
    for (int j = 0; j < 16; ++j) {
        const int q = (j << 2) + qg;
        const float pv = s[j] * inv;
        const float4* v4 = (const float4*)(sV + q * HPITCH);
#pragma unroll
        for (int d = 0; d < 8; ++d) {
            const float4 vv = v4[d];
            part[d].x = fmaf(pv, vv.x, part[d].x);
            part[d].y = fmaf(pv, vv.y, part[d].y);
            part[d].z = fmaf(pv, vv.z, part[d].z);
            part[d].w = fmaf(pv, vv.w, part[d].w);
        }
    }
#pragma unroll
    for (int d = 0; d < 8; ++d) {
        part[d].x += __shfl_xor(part[d].x, 1); part[d].x += __shfl_xor(part[d].x, 2);
        part[d].y += __shfl_xor(part[d].y, 1); part[d].y += __shfl_xor(part[d].y, 2);
        part[d].z += __shfl_xor(part[d].z, 1); part[d].z += __shfl_xor(part[d].z, 2);
        part[d].w += __shfl_xor(part[d].w, 1); part[d].w += __shfl_xor(part[d].w, 2);
    }
    // lane qg writes head-dim quads 2*qg, 2*qg+1 (static reg indices)
    float4 w0 = part[0], w1 = part[1];
    if (qg == 1) { w0 = part[2]; w1 = part[3]; }
    else if (qg == 2) { w0 = part[4]; w1 = part[5]; }
    else if (qg == 3) { w0 = part[6]; w1 = part[7]; }
    float4* o4 = (float4*)(sQO + p * HPITCH);
    o4[(qg << 1) + 0] = w0;
    o4[(qg << 1) + 1] = w1;
}

// Out-projection partial: yacc[i] += O_head[r][:] . w_out[cb+i][h*32 + :]
__device__ __forceinline__ void projAcc(const float* __restrict__ sO,
                                        const float* __restrict__ wo,  // global w_out + h*32
                                        float* __restrict__ yacc, int t)
{
    const int r = t & 63;
    const int cb = (t >> 6) * 48;
    const float4* o4 = (const float4*)(sO + r * HPITCH);
    float4 oreg[8];
#pragma unroll
    for (int j = 0; j < 8; ++j) oreg[j] = o4[j];
    const float4* wr = (const float4*)(wo + cb * CDIM);
#pragma unroll
    for (int i = 0; i < 48; ++i) {
        float a = 0.f;
#pragma unroll
        for (int j = 0; j < 8; ++j) {
            const float4 wv = wr[j];
            a = fmaf(oreg[j].x, wv.x, a);
            a = fmaf(oreg[j].y, wv.y, a);
            a = fmaf(oreg[j].z, wv.z, a);
            a = fmaf(oreg[j].w, wv.w, a);
        }
        yacc[i] += a;
        wr += 48;                            // next w_out row (768 B)
    }
}

__global__ __launch_bounds__(256, 2)
void wmca_fused(const float* __restrict__ x, const float* __restrict__ bten,
                const float* __restrict__ w_qkv, const float* __restrict__ b_qkv,
                const float* __restrict__ w_qkv_b, const float* __restrict__ b_qkv_b,
                const float* __restrict__ rel, const float* __restrict__ w_out,
                const float* __restrict__ b_out, float* __restrict__ out)
{
    __shared__ float sX[64 * XPITCH];
    __shared__ float sQO[64 * HPITCH];   // Q, then O
    __shared__ float sK[64 * HPITCH];
    __shared__ float sV[64 * HPITCH];

    const int t = threadIdx.x;
    const int wid = blockIdx.x;
    const int bi = wid >> 10;
    const int whi = (wid >> 5) & 31;
    const int wwi = wid & 31;
    const bool lastrow = (whi == 31);
    const bool lastcol = (wwi == 31);

    // per-thread row base (row r = t&63 of the window) for b reads + out writes
    const int r63 = t & 63;
    const int prG = r63 >> 3, pcG = r63 & 7;
    const int hoG = (whi * 8 + prG + SHIFTV) & 255;
    const int woG = (wwi * 8 + pcG + SHIFTV) & 255;
    const int pixBase = ((bi * IMG + hoG) * IMG + woG) * CDIM;
    const float4* bRow = (const float4*)(bten + pixBase);

    // ---- stage x window (cyclic shift folded into gather) ----
    {
        const int rr = t >> 2, part = t & 3;
        const int pr = rr >> 3, pc = rr & 7;
        const int ho = (whi * 8 + pr + SHIFTV) & 255;
        const int wo = (wwi * 8 + pc + SHIFTV) & 255;
        const float4* xs = (const float4*)(x + ((bi * IMG + ho) * IMG + wo) * CDIM);
        float4* dX = (float4*)(sX + rr * XPITCH);
#pragma unroll
        for (int i = 0; i < 12; ++i) {
            const int q = part + (i << 2);
            dX[q] = xs[q];
        }
    }

    float yacc[48];
#pragma unroll
    for (int i = 0; i < 48; ++i) yacc[i] = 0.f;

    __syncthreads();                                     // sX ready

    for (int h = 0; h < NHEADS; ++h) {
        gemmG(bRow, w_qkv_b + (h * 32) * CDIM, b_qkv_b + h * 32, sQO, t);
        gemmL(sX, w_qkv + (CDIM + h * 32) * CDIM, b_qkv + CDIM + h * 32, sK, t);
        gemmL(sX, w_qkv + (2 * CDIM + h * 32) * CDIM, b_qkv + 2 * CDIM + h * 32, sV, t);
        __syncthreads();                                 // Q,K,V visible
        attnHead(sQO, sK, sV, rel + h * 225, lastrow, lastcol, t);
        __syncthreads();                                 // O visible
        projAcc(sQO, w_out + h * 32, yacc, t);
        __syncthreads();                                 // proj reads done
    }

    // ---- write output (inverse roll folded into scatter coords) ----
    {
        const int cb = (t >> 6) * 48;
        float4* dst = (float4*)(out + pixBase + cb);
        const float4* bo = (const float4*)(b_out + cb);
#pragma unroll
        for (int i4 = 0; i4 < 12; ++i4) {
            float4 v = bo[i4];
            v.x += yacc[i4 * 4 + 0];
            v.y += yacc[i4 * 4 + 1];
            v.z += yacc[i4 * 4 + 2];
            v.w += yacc[i4 * 4 + 3];
            dst[i4] = v;
        }
    }
}

extern "C" void kernel_launch(void* const* d_in, const int* in_sizes, int n_in,
                              void* d_out, int out_size, void* d_ws, size_t ws_size,
                              hipStream_t stream)
{
    const float* x       = (const float*)d_in[0];
    const float* b       = (const float*)d_in[1];
    const float* w_qkv   = (const float*)d_in[2];
    const float* b_qkv   = (const float*)d_in[3];
    const float* w_qkv_b = (const float*)d_in[4];
    const float* b_qkv_b = (const float*)d_in[5];
    const float* rel     = (const float*)d_in[6];
    const float* w_out   = (const float*)d_in[7];
    const float* b_out   = (const float*)d_in[8];
    float* out = (float*)d_out;

    wmca_fused<<<dim3(2048), dim3(256), 0, stream>>>(
        x, b, w_qkv, b_qkv, w_qkv_b, b_qkv_b, rel, w_out, b_out, out);
}

// Round 5
// 514.221 us; speedup vs baseline: 5.1859x; 5.1859x over previous
//
#include <hip/hip_runtime.h>

// Fused shifted-window cross-attention, MFMA fp16-input/fp32-accum rewrite.
// One block per 8x8 window (2048 blocks, 4 waves). Per head: Q/K GEMMs,
// V computed transposed (operand-swapped MFMA) so PV reads V^T rows natively,
// QK^T with bias+mask table as MFMA C-init (scale folded into Q), in-register
// softmax (C-layout, 16-lane shfl_xor), PV, out-proj accumulated in MFMA C
// across heads. Weights pre-converted to fp16 in d_ws; bias/mask table
// precomputed per (window-type, head). LDS 49.7KB -> 3 blocks/CU.
// [resubmit: round-3 bench died on GPU acquisition; source re-audited, no
//  defects found — needs its first measurement]

#define NHEADS 6
#define CDIM 192
#define IMG 256
#define SHIFTV 4
#define SCALE_F 0.17677669529663687f

typedef __attribute__((ext_vector_type(8))) _Float16 h8;
typedef __attribute__((ext_vector_type(4))) _Float16 h4;
typedef __attribute__((ext_vector_type(4))) float f4;

#define MFMA(a, b, c) __builtin_amdgcn_mfma_f32_16x16x32_f16((a), (b), (c), 0, 0, 0)

// ===== prep: weights fp32 -> fp16 (n-major rows), 4 x 192x192 =====
__global__ void prep_weights(const float* __restrict__ wqb,
                             const float* __restrict__ wqkv,
                             const float* __restrict__ wout,
                             _Float16* __restrict__ dst)
{
    const int i = blockIdx.x * 256 + threadIdx.x;        // 0..147455
    const int m = i / 36864, r = i - m * 36864;
    float v;
    if (m == 0)      v = wqb[r];                         // Wq  = w_qkv_b rows 0..191
    else if (m == 1) v = wqkv[36864 + r];                // Wk  = w_qkv rows 192..383
    else if (m == 2) v = wqkv[73728 + r];                // Wv  = w_qkv rows 384..575
    else             v = wout[r];                        // Wo
    dst[i] = (_Float16)v;
}

// ===== prep: bias+mask table [type][head][q][k] f32 (mask -> -1e30) =====
__global__ void prep_table(const float* __restrict__ rel, float* __restrict__ tab)
{
    const int i = blockIdx.x * 256 + threadIdx.x;        // 4*6*64*64 = 98304
    const int k = i & 63, q = (i >> 6) & 63;
    const int th = i >> 12;                              // ty*6 + h
    const int h = th % 6, ty = th / 6;
    const int pr = q >> 3, pc = q & 7, qr = k >> 3, qc = k & 7;
    const bool msk = ((ty & 1) && ((pr < 4) != (qr < 4))) ||
                     ((ty & 2) && ((pc < 4) != (qc < 4)));
    const float bias = rel[h * 225 + (pr - qr + 7) * 15 + (pc - qc + 7)];
    tab[i] = msk ? -1e30f : bias;
}

// ===== main fused kernel =====
__global__ __launch_bounds__(256, 3)
void wmca_mfma(const float* __restrict__ x, const float* __restrict__ bten,
               const float* __restrict__ b_qkv, const float* __restrict__ b_qkv_b,
               const float* __restrict__ b_out,
               const _Float16* __restrict__ wh, const float* __restrict__ tab,
               float* __restrict__ out)
{
    __shared__ _Float16 sX[64 * 200];   // x window rows (pitch 200: aligned+spread)
    __shared__ _Float16 sQ[64 * 40];    // Q (scaled), later O — wave-private rows
    __shared__ _Float16 sK[64 * 40];
    __shared__ _Float16 sVt[32 * 72];   // V transposed [c][token]
    __shared__ _Float16 sP[64 * 72];    // probs [q][k]

    const int t = threadIdx.x;
    const int w = t >> 6, l = t & 63, g = l >> 4, c16 = l & 15;

    const int wid = blockIdx.x;
    const int bi = wid >> 10, whi = (wid >> 5) & 31, wwi = wid & 31;
    const int ty = ((whi == 31) ? 1 : 0) | ((wwi == 31) ? 2 : 0);

    // ---- stage x window -> fp16 LDS (cyclic shift folded into gather) ----
    {
        const int rr = t >> 2, part = t & 3;
        const int pr = rr >> 3, pc = rr & 7;
        const int ho = (whi * 8 + pr + SHIFTV) & 255;
        const int wo = (wwi * 8 + pc + SHIFTV) & 255;
        const float4* xs = (const float4*)(x + ((bi * IMG + ho) * IMG + wo) * CDIM);
        _Float16* dX = sX + rr * 200;
#pragma unroll
        for (int i = 0; i < 12; ++i) {
            const int q4 = part + 4 * i;
            const float4 v = xs[q4];
            h4 hv; hv[0] = (_Float16)v.x; hv[1] = (_Float16)v.y;
                   hv[2] = (_Float16)v.z; hv[3] = (_Float16)v.w;
            *(h4*)(dX + 4 * q4) = hv;
        }
    }

    // ---- per-lane b-row base; hoist Q A-frags (head-independent) ----
    const int tokA = 16 * w + c16;
    const int prA = tokA >> 3, pcA = tokA & 7;
    const int hoA = (whi * 8 + prA + SHIFTV) & 255;
    const int woA = (wwi * 8 + pcA + SHIFTV) & 255;
    const float* bA = bten + ((bi * IMG + hoA) * IMG + woA) * CDIM;

    h8 aQ[6];
#pragma unroll
    for (int ks = 0; ks < 6; ++ks) {
        const float4 f0 = *(const float4*)(bA + ks * 32 + 8 * g);
        const float4 f1 = *(const float4*)(bA + ks * 32 + 8 * g + 4);
        h8 a;
        a[0] = (_Float16)f0.x; a[1] = (_Float16)f0.y;
        a[2] = (_Float16)f0.z; a[3] = (_Float16)f0.w;
        a[4] = (_Float16)f1.x; a[5] = (_Float16)f1.y;
        a[6] = (_Float16)f1.z; a[7] = (_Float16)f1.w;
        aQ[ks] = a;
    }

    // ---- proj accumulators (b_out folded in once) ----
    f4 pacc[12];
#pragma unroll
    for (int nt = 0; nt < 12; ++nt) {
        const float bo = b_out[16 * nt + c16];
        pacc[nt] = (f4){bo, bo, bo, bo};
    }

    const _Float16* Wq = wh;
    const _Float16* Wk = wh + 36864;
    const _Float16* Wv = wh + 2 * 36864;
    const _Float16* Wo = wh + 3 * 36864;
    const int vm = w & 1, vn = w >> 1;

    __syncthreads();

    for (int h = 0; h < NHEADS; ++h) {
        // ---- Q = b @ Wq^T (+bias), scaled; wave owns token stripe 16w.. ----
        {
            const float b0 = b_qkv_b[h * 32 + c16];
            const float b1 = b_qkv_b[h * 32 + 16 + c16];
            f4 a0 = {b0, b0, b0, b0}, a1 = {b1, b1, b1, b1};
            const _Float16* wr0 = Wq + (h * 32 + c16) * 192 + 8 * g;
            const _Float16* wr1 = wr0 + 16 * 192;
#pragma unroll
            for (int ks = 0; ks < 6; ++ks) {
                a0 = MFMA(aQ[ks], *(const h8*)(wr0 + ks * 32), a0);
                a1 = MFMA(aQ[ks], *(const h8*)(wr1 + ks * 32), a1);
            }
#pragma unroll
            for (int rg = 0; rg < 4; ++rg) {
                sQ[(16 * w + 4 * g + rg) * 40 + c16]      = (_Float16)(a0[rg] * SCALE_F);
                sQ[(16 * w + 4 * g + rg) * 40 + 16 + c16] = (_Float16)(a1[rg] * SCALE_F);
            }
        }
        // ---- K = x @ Wk^T (+bias) ----
        {
            const float b0 = b_qkv[CDIM + h * 32 + c16];
            const float b1 = b_qkv[CDIM + h * 32 + 16 + c16];
            f4 a0 = {b0, b0, b0, b0}, a1 = {b1, b1, b1, b1};
            const _Float16* xr = sX + (16 * w + c16) * 200 + 8 * g;
            const _Float16* wr0 = Wk + (h * 32 + c16) * 192 + 8 * g;
            const _Float16* wr1 = wr0 + 16 * 192;
#pragma unroll
            for (int ks = 0; ks < 6; ++ks) {
                const h8 a = *(const h8*)(xr + ks * 32);
                a0 = MFMA(a, *(const h8*)(wr0 + ks * 32), a0);
                a1 = MFMA(a, *(const h8*)(wr1 + ks * 32), a1);
            }
#pragma unroll
            for (int rg = 0; rg < 4; ++rg) {
                sK[(16 * w + 4 * g + rg) * 40 + c16]      = (_Float16)a0[rg];
                sK[(16 * w + 4 * g + rg) * 40 + 16 + c16] = (_Float16)a1[rg];
            }
        }
        // ---- V^T = Wv @ x^T (+bias): operand-swapped, D lands transposed ----
        {
            const float4 bv = *(const float4*)(b_qkv + 2 * CDIM + h * 32 + 16 * vm + 4 * g);
            f4 a0 = {bv.x, bv.y, bv.z, bv.w};
            f4 a1 = a0;
            const _Float16* wr = Wv + (h * 32 + 16 * vm + c16) * 192 + 8 * g;
            const _Float16* x0 = sX + (32 * vn + c16) * 200 + 8 * g;
            const _Float16* x1 = x0 + 16 * 200;
#pragma unroll
            for (int ks = 0; ks < 6; ++ks) {
                const h8 a = *(const h8*)(wr + ks * 32);
                a0 = MFMA(a, *(const h8*)(x0 + ks * 32), a0);
                a1 = MFMA(a, *(const h8*)(x1 + ks * 32), a1);
            }
#pragma unroll
            for (int rg = 0; rg < 4; ++rg) {
                sVt[(16 * vm + 4 * g + rg) * 72 + 32 * vn + c16]      = (_Float16)a0[rg];
                sVt[(16 * vm + 4 * g + rg) * 72 + 32 * vn + 16 + c16] = (_Float16)a1[rg];
            }
        }
        __syncthreads();

        // ---- S = Q@K^T + table (C-init carries rel-bias and -1e30 mask) ----
        {
            const float* tr = tab + ((ty * 6 + h) << 12) + (16 * w + 4 * g) * 64 + c16;
            f4 s0, s1, s2, s3;
#pragma unroll
            for (int rg = 0; rg < 4; ++rg) {
                s0[rg] = tr[rg * 64];
                s1[rg] = tr[rg * 64 + 16];
                s2[rg] = tr[rg * 64 + 32];
                s3[rg] = tr[rg * 64 + 48];
            }
            const h8 qa = *(const h8*)(sQ + (16 * w + c16) * 40 + 8 * g);
            s0 = MFMA(qa, *(const h8*)(sK + c16 * 40 + 8 * g), s0);
            s1 = MFMA(qa, *(const h8*)(sK + (16 + c16) * 40 + 8 * g), s1);
            s2 = MFMA(qa, *(const h8*)(sK + (32 + c16) * 40 + 8 * g), s2);
            s3 = MFMA(qa, *(const h8*)(sK + (48 + c16) * 40 + 8 * g), s3);
            // softmax per query row (C-layout: rows 4g+rg, cols c16+16nt)
#pragma unroll
            for (int rg = 0; rg < 4; ++rg) {
                float mx = fmaxf(fmaxf(s0[rg], s1[rg]), fmaxf(s2[rg], s3[rg]));
                mx = fmaxf(mx, __shfl_xor(mx, 1));
                mx = fmaxf(mx, __shfl_xor(mx, 2));
                mx = fmaxf(mx, __shfl_xor(mx, 4));
                mx = fmaxf(mx, __shfl_xor(mx, 8));
                const float e0 = __expf(s0[rg] - mx);
                const float e1 = __expf(s1[rg] - mx);
                const float e2 = __expf(s2[rg] - mx);
                const float e3 = __expf(s3[rg] - mx);
                float sm = e0 + e1 + e2 + e3;
                sm += __shfl_xor(sm, 1);
                sm += __shfl_xor(sm, 2);
                sm += __shfl_xor(sm, 4);
                sm += __shfl_xor(sm, 8);
                const float inv = 1.0f / sm;
                _Float16* prow = sP + (16 * w + 4 * g + rg) * 72 + c16;
                prow[0]  = (_Float16)(e0 * inv);
                prow[16] = (_Float16)(e1 * inv);
                prow[32] = (_Float16)(e2 * inv);
                prow[48] = (_Float16)(e3 * inv);
            }
        }

        // ---- O = P @ V (B-frags are V^T rows); O into sQ (wave-private) ----
        {
            const h8 pa0 = *(const h8*)(sP + (16 * w + c16) * 72 + 8 * g);
            const h8 pa1 = *(const h8*)(sP + (16 * w + c16) * 72 + 32 + 8 * g);
            f4 o0 = {0.f, 0.f, 0.f, 0.f}, o1 = o0;
            o0 = MFMA(pa0, *(const h8*)(sVt + c16 * 72 + 8 * g), o0);
            o0 = MFMA(pa1, *(const h8*)(sVt + c16 * 72 + 32 + 8 * g), o0);
            o1 = MFMA(pa0, *(const h8*)(sVt + (16 + c16) * 72 + 8 * g), o1);
            o1 = MFMA(pa1, *(const h8*)(sVt + (16 + c16) * 72 + 32 + 8 * g), o1);
#pragma unroll
            for (int rg = 0; rg < 4; ++rg) {
                sQ[(16 * w + 4 * g + rg) * 40 + c16]      = (_Float16)o0[rg];
                sQ[(16 * w + 4 * g + rg) * 40 + 16 + c16] = (_Float16)o1[rg];
            }
        }
        __syncthreads();   // protects sK/sVt rewrite next head (all reads done)

        // ---- out-projection: pacc[nt] += O_head @ Wo_slice ----
        {
            const h8 oa = *(const h8*)(sQ + (16 * w + c16) * 40 + 8 * g);
            const _Float16* wr = Wo + c16 * 192 + h * 32 + 8 * g;
#pragma unroll
            for (int nt = 0; nt < 12; ++nt)
                pacc[nt] = MFMA(oa, *(const h8*)(wr + nt * 16 * 192), pacc[nt]);
        }
    }

    // ---- write out (inverse roll folded into scatter) ----
#pragma unroll
    for (int rg = 0; rg < 4; ++rg) {
        const int token = 16 * w + 4 * g + rg;
        const int pr = token >> 3, pc = token & 7;
        const int ho = (whi * 8 + pr + SHIFTV) & 255;
        const int wo = (wwi * 8 + pc + SHIFTV) & 255;
        float* po = out + ((bi * IMG + ho) * IMG + wo) * CDIM + c16;
#pragma unroll
        for (int nt = 0; nt < 12; ++nt)
            po[16 * nt] = pacc[nt][rg];
    }
}

extern "C" void kernel_launch(void* const* d_in, const int* in_sizes, int n_in,
                              void* d_out, int out_size, void* d_ws, size_t ws_size,
                              hipStream_t stream)
{
    const float* x       = (const float*)d_in[0];
    const float* b       = (const float*)d_in[1];
    const float* w_qkv   = (const float*)d_in[2];
    const float* b_qkv   = (const float*)d_in[3];
    const float* w_qkv_b = (const float*)d_in[4];
    const float* b_qkv_b = (const float*)d_in[5];
    const float* rel     = (const float*)d_in[6];
    const float* w_out   = (const float*)d_in[7];
    const float* b_out   = (const float*)d_in[8];
    float* out = (float*)d_out;

    _Float16* wh = (_Float16*)d_ws;                      // 4 x 36864 fp16 = 294912 B
    float* tab = (float*)((char*)d_ws + 294912);         // 98304 f32 = 393216 B

    prep_weights<<<576, 256, 0, stream>>>(w_qkv_b, w_qkv, w_out, wh);
    prep_table<<<384, 256, 0, stream>>>(rel, tab);
    wmca_mfma<<<2048, 256, 0, stream>>>(x, b, b_qkv, b_qkv_b, b_out, wh, tab, out);
}